// Round 11
// baseline (71.827 us; speedup 1.0000x reference)
//
#include <hip/hip_runtime.h>
#include <hip/hip_bf16.h>
#include <stdint.h>

#define Bsz 128
#define Tn  512
#define In  700
#define On  128
#define Mn  (Bsz * Tn)   // 65536
#define KP  704          // K padded to multiple of 32
#define NSEG 16
#define LSEG 32          // Tn / NSEG
#define BO   (Bsz * On)  // 16384 chains
#define NKT  22          // K tiles of 32
#define BM   64          // rows per block (2 segments of one batch)

using bf16x8 = __attribute__((ext_vector_type(8))) short;
using f32x4  = __attribute__((ext_vector_type(4))) float;

#define WAITVM(N) asm volatile("s_waitcnt vmcnt(" #N ")" ::: "memory")

__device__ __forceinline__ uint32_t f2bf(float f) {
  union { float f; uint32_t u; } v; v.f = f;
  return (v.u + 0x7fffu + ((v.u >> 16) & 1u)) >> 16;   // RNE
}

// pairwise f32->bf16 via v_cvt_pk_bf16_f32 (compiler-generated, RNE)
__device__ __forceinline__ bf16x8 cvt8(float4 f0, float4 f1) {
  union { __hip_bfloat162 h2[4]; bf16x8 v; } u;
  u.h2[0] = __float22bfloat162_rn(make_float2(f0.x, f0.y));
  u.h2[1] = __float22bfloat162_rn(make_float2(f0.z, f0.w));
  u.h2[2] = __float22bfloat162_rn(make_float2(f1.x, f1.y));
  u.h2[3] = __float22bfloat162_rn(make_float2(f1.z, f1.w));
  return u.v;
}

// async global->LDS, 16B per lane; LDS dest = wave-uniform base + lane*16
__device__ __forceinline__ void gload16(const void* g, void* l) {
  __builtin_amdgcn_global_load_lds(
      (__attribute__((address_space(1))) void*)g,
      (__attribute__((address_space(3))) void*)l, 16, 0, 0);
}

// ---- prep: w (700x128 f32, k-major) -> w_t (128 x 704 bf16, zero-padded K) ----
__global__ void prep_wt(const float* __restrict__ w, ushort* __restrict__ w_t) {
  int idx = blockIdx.x * 256 + threadIdx.x;
  if (idx >= On * KP) return;
  int col = idx / KP, k = idx - col * KP;
  float v = (k < In) ? w[(size_t)k * On + col] : 0.0f;
  w_t[(size_t)col * KP + k] = (ushort)f2bf(v);
}

// ========== GEMM: BM=64, 1024 blocks, 3-deep counted-vmcnt, 3 blocks/CU ==========
union SMU {
  struct {
    uint32_t A[3][2048];   // 24 KB: fp32 tile 64 rows x 8 slots x 16B, src-swizzled
    uint32_t B[3][2048];   // 24 KB: bf16 tile 128 cols x 4 slots x 16B, src-swizzled
  } db;                    // 48 KB staging
  float sc[BM * 132];      // 33.8 KB h/scan buffer (pad 132)
};

__global__ __launch_bounds__(256, 3) void gemm_h(
    const float* __restrict__ A,    // 65536 x 700 f32
    const ushort* __restrict__ Wt,  // 128 x 704 bf16
    float* __restrict__ Hf,         // fp32 h out (syn region)
    float2* __restrict__ ep,        // [NSEG][BO] endpoints (may be null)
    const float* __restrict__ alpha, const float* __restrict__ beta)
{
  __shared__ __align__(16) SMU sm;

  const int tid  = threadIdx.x;
  const int bm   = blockIdx.x;        // 1024 blocks: batch b = bm>>3, eighth = bm&7
  const int lane = tid & 63;
  const int wid  = tid >> 6;          // 4 waves, 2x2 wave grid (32x64 each)
  const int wm   = wid >> 1, wn = wid & 1;
  const int l16  = lane & 15, lkb = lane >> 4;

  // alpha/beta for phase A; drain so the counted vmcnt pipeline stays exact
  const int   o_ep = tid & 127;
  const float a_ep = alpha[o_ep];
  const float b_ep = beta[o_ep];
  WAITVM(0);
  __builtin_amdgcn_sched_barrier(0);

  f32x4 acc[2][4];
#pragma unroll
  for (int i = 0; i < 2; ++i)
#pragma unroll
    for (int n = 0; n < 4; ++n) acc[i][n] = (f32x4){0.f, 0.f, 0.f, 0.f};

  auto stage = [&](int bi, int kt) {   // 4 loads per wave (2 A + 2 B)
    const int k0 = kt * 32;
    // A: 64 rows x 32 k fp32 = 8 KB = 2 wave-issues of 16B/lane
#pragma unroll
    for (int is = 0; is < 2; ++is) {
      const int q   = is * 256 + wid * 64 + lane;   // 0..511
      const int row = q >> 3, sl = q & 7;
      int gk = k0 + ((sl ^ (row & 7)) << 2);
      if (gk >= In) gk = k0;                        // clamp; Wt zero at k>=700
      gload16(A + (size_t)(bm * BM + row) * In + gk,
              &sm.db.A[bi][is * 1024 + wid * 256]);
    }
    // B: 128 cols x 32 k bf16 = 8 KB = 2 wave-issues
#pragma unroll
    for (int is = 0; is < 2; ++is) {
      const int q   = is * 256 + wid * 64 + lane;
      const int col = q >> 2, sl = q & 3;
      const int ks  = sl ^ ((col >> 1) & 3);
      gload16(Wt + (size_t)col * KP + k0 + ks * 8,
              &sm.db.B[bi][is * 1024 + wid * 256]);
    }
  };

  auto tile = [&](int kt, int cur) {
    __builtin_amdgcn_s_barrier();
    const float4* Af = (const float4*)sm.db.A[cur];   // idx = row*8 + slot
    const bf16x8* Bf = (const bf16x8*)sm.db.B[cur];   // idx = col*4 + slot
    bf16x8 af[2], bfr[4];
#pragma unroll
    for (int i = 0; i < 2; ++i) {
      const int row = wm * 32 + i * 16 + l16;
      const int s0  = (lkb * 2) ^ (row & 7);
      const int s1  = (lkb * 2 + 1) ^ (row & 7);
      af[i] = cvt8(Af[row * 8 + s0], Af[row * 8 + s1]);
    }
#pragma unroll
    for (int n = 0; n < 4; ++n) {
      const int col = wn * 64 + n * 16 + l16;
      bfr[n] = Bf[col * 4 + (lkb ^ ((col >> 1) & 3))];
    }
    asm volatile("s_waitcnt lgkmcnt(0)" ::: "memory");
    __builtin_amdgcn_s_barrier();
    if (kt + 3 < NKT) stage(cur, kt + 3);   // overwrite just-consumed buffer
#pragma unroll
    for (int i = 0; i < 2; ++i)
#pragma unroll
      for (int n = 0; n < 4; ++n)
        acc[i][n] = __builtin_amdgcn_mfma_f32_16x16x32_bf16(af[i], bfr[n], acc[i][n], 0, 0, 0);
  };

  stage(0, 0); stage(1, 1); stage(2, 2);    // 12 loads/wave in flight
  {
    int cur = 0;
    for (int kt = 0; kt < NKT - 2; ++kt) {  // kt = 0..19: 3 tiles outstanding
      WAITVM(8);
      tile(kt, cur);
      cur = (cur == 2) ? 0 : cur + 1;
    }
    WAITVM(4);  tile(NKT - 2, (NKT - 2) % 3);
    WAITVM(0);  tile(NKT - 1, (NKT - 1) % 3);
  }

  // ---- epilogue: acc -> LDS (t-major, pad 132) ----
#pragma unroll
  for (int i = 0; i < 2; ++i)
#pragma unroll
    for (int n = 0; n < 4; ++n) {
      const int col = wn * 64 + n * 16 + l16;
#pragma unroll
      for (int r = 0; r < 4; ++r) {
        const int row = wm * 32 + i * 16 + lkb * 4 + r;
        sm.sc[row * 132 + col] = acc[i][n][r];
      }
    }
  __syncthreads();

  // coalesced float4 H write from LDS (64 rows x 32 float4-slots)
  const size_t hbase = (size_t)bm * BM * 128;
#pragma unroll
  for (int i2 = 0; i2 < 8; ++i2) {
    const int q = i2 * 256 + tid;
    const int row = q >> 5, v = q & 31;
    *(float4*)&Hf[hbase + row * 128 + v * 4] =
        *(const float4*)&sm.sc[row * 132 + v * 4];
  }

  // fused phase A: per-segment local scan from zero (2 segs x 128 cols)
  if (ep) {
    const float a = a_ep, bt = b_ep, omb = 1.0f - b_ep;
    const int b = bm >> 3, seg0 = (bm & 7) * 2;
    const int sl = tid >> 7;                  // 0 or 1
    float S = 0.f, M = 0.f;
    const float* base = &sm.sc[(sl * 32) * 132 + o_ep];
#pragma unroll
    for (int t = 0; t < 32; ++t) {
      const float x = base[t * 132];
      M = fmaf(bt, M, omb * S);   // uses OLD S
      S = fmaf(a, S, x);
    }
    ep[(size_t)(seg0 + sl) * BO + b * On + o_ep] = make_float2(S, M);
  }
}

// ---- Phase B+C fused, float2-vectorized (round-6 proven) ----
__global__ __launch_bounds__(256) void scan_seg(
    float* __restrict__ syn, float* __restrict__ mem, const float2* __restrict__ ep,
    const float* __restrict__ alpha, const float* __restrict__ beta)
{
  const int cid = blockIdx.x * 256 + threadIdx.x;   // (b, seg, o2): 128*16*64
  const int o2  = cid & 63;
  const int seg = (cid >> 6) & (NSEG - 1);
  const int b   = cid >> 10;
  const int o   = 2 * o2;

  const float2 al2 = *(const float2*)&alpha[o];
  const float2 be2 = *(const float2*)&beta[o];
  const float a0 = al2.x, a1 = al2.y, b0 = be2.x, b1 = be2.y;
  const float ob0 = 1.f - b0, ob1 = 1.f - b1;

  float aL0 = 1.f, bL0 = 1.f, cL0 = 0.f, aL1 = 1.f, bL1 = 1.f, cL1 = 0.f;
#pragma unroll
  for (int i = 0; i < LSEG; ++i) {
    cL0 = fmaf(b0, cL0, ob0 * aL0); aL0 *= a0; bL0 *= b0;
    cL1 = fmaf(b1, cL1, ob1 * aL1); aL1 *= a1; bL1 *= b1;
  }

  float S0 = 0.f, M0 = 0.f, S1 = 0.f, M1 = 0.f;
  for (int j = 0; j < seg; ++j) {
    const float4 E = *(const float4*)&ep[(size_t)j * BO + b * On + o];
    const float nS0 = fmaf(aL0, S0, E.x);
    M0 = fmaf(bL0, M0, fmaf(cL0, S0, E.y));   // uses OLD S
    S0 = nS0;
    const float nS1 = fmaf(aL1, S1, E.z);
    M1 = fmaf(bL1, M1, fmaf(cL1, S1, E.w));
    S1 = nS1;
  }

  float* hp = syn + ((size_t)b * Tn + seg * LSEG) * On + o;  // holds h, becomes S
  float* mp = mem + ((size_t)b * Tn + seg * LSEG) * On + o;
  float2 buf[8];
#pragma unroll
  for (int d = 0; d < 8; ++d) buf[d] = *(const float2*)&hp[d * On];
  for (int tb = 0; tb < LSEG; tb += 8) {
#pragma unroll
    for (int d = 0; d < 8; ++d) {
      const int t = tb + d;
      const float2 x = buf[d];
      if (t + 8 < LSEG) buf[d] = *(const float2*)&hp[(t + 8) * On];
      *(float2*)&hp[(size_t)t * On] = make_float2(S0, S1);
      *(float2*)&mp[(size_t)t * On] = make_float2(M0, M1);
      M0 = fmaf(b0, M0, ob0 * S0); S0 = fmaf(a0, S0, x.x);   // M uses OLD S
      M1 = fmaf(b1, M1, ob1 * S1); S1 = fmaf(a1, S1, x.y);
    }
  }
}

// ---- fallback single-pass scan (used only if ws_size is tiny) ----
__global__ __launch_bounds__(64) void scan_k(
    float* __restrict__ syn, float* __restrict__ mem,
    const float* __restrict__ alpha, const float* __restrict__ beta)
{
  const int b = blockIdx.x >> 1;
  const int o = ((blockIdx.x & 1) << 6) + threadIdx.x;
  const float a = alpha[o], bt = beta[o], omb = 1.0f - bt;
  float* hp = syn + (size_t)b * Tn * On + o;
  float* mp = mem + (size_t)b * Tn * On + o;
  float S = 0.f, M = 0.f;
  float buf[8];
#pragma unroll
  for (int d = 0; d < 8; ++d) buf[d] = hp[d * On];
  for (int tb = 0; tb < Tn; tb += 8) {
#pragma unroll
    for (int d = 0; d < 8; ++d) {
      const int t = tb + d;
      const float h_t = buf[d];
      if (t + 8 < Tn) buf[d] = hp[(t + 8) * On];
      hp[t * On] = S;
      mp[t * On] = M;
      const float nS = fmaf(a, S, h_t);
      M = fmaf(bt, M, omb * S);
      S = nS;
    }
  }
}

extern "C" void kernel_launch(void* const* d_in, const int* in_sizes, int n_in,
                              void* d_out, int out_size, void* d_ws, size_t ws_size,
                              hipStream_t stream) {
  const float* inputs = (const float*)d_in[0];   // (128,512,700)
  const float* w      = (const float*)d_in[1];   // (700,128)
  const float* alpha  = (const float*)d_in[2];   // (1,128)
  const float* beta   = (const float*)d_in[3];   // (1,128)

  float* syn = (float*)d_out;                    // first 8M floats
  float* mem = syn + (size_t)Bsz * Tn * On;      // next 8M floats
  ushort* w_t = (ushort*)mem;                    // 180 KB temp in mem region,
                                                 // consumed by gemm before scan writes

  const size_t ep_bytes = (size_t)NSEG * BO * sizeof(float2);  // 2 MB
  float2* ep = (ws_size >= ep_bytes) ? (float2*)d_ws : nullptr;

  prep_wt<<<(On * KP + 255) / 256, 256, 0, stream>>>(w, w_t);
  gemm_h<<<Mn / BM, 256, 0, stream>>>(inputs, w_t, syn, ep, alpha, beta);

  if (ep) {
    scan_seg<<<(Bsz * NSEG * On / 2) / 256, 256, 0, stream>>>(syn, mem, ep, alpha, beta);
  } else {
    scan_k<<<Bsz * 2, 64, 0, stream>>>(syn, mem, alpha, beta);
  }
}

// Round 12
// 61.635 us; speedup vs baseline: 1.1654x; 1.1654x over previous
//
#include <hip/hip_runtime.h>
#include <hip/hip_bf16.h>
#include <stdint.h>

#define Bsz 128
#define Tn  512
#define In  700
#define On  128
#define Mn  (Bsz * Tn)   // 65536
#define KP  704          // K padded to multiple of 32
#define NSEG 16
#define LSEG 32          // Tn / NSEG
#define BO   (Bsz * On)  // 16384 chains
#define NKT  22          // K tiles of 32

using bf16x8 = __attribute__((ext_vector_type(8))) short;
using f32x4  = __attribute__((ext_vector_type(4))) float;
using f32x2  = __attribute__((ext_vector_type(2))) float;

#define WAITVM(N) asm volatile("s_waitcnt vmcnt(" #N ")" ::: "memory")

__device__ __forceinline__ uint32_t f2bf(float f) {
  union { float f; uint32_t u; } v; v.f = f;
  return (v.u + 0x7fffu + ((v.u >> 16) & 1u)) >> 16;   // RNE
}

// pairwise f32->bf16 via v_cvt_pk_bf16_f32 (compiler-generated, RNE)
__device__ __forceinline__ bf16x8 cvt8(float4 f0, float4 f1) {
  union { __hip_bfloat162 h2[4]; bf16x8 v; } u;
  u.h2[0] = __float22bfloat162_rn(make_float2(f0.x, f0.y));
  u.h2[1] = __float22bfloat162_rn(make_float2(f0.z, f0.w));
  u.h2[2] = __float22bfloat162_rn(make_float2(f1.x, f1.y));
  u.h2[3] = __float22bfloat162_rn(make_float2(f1.z, f1.w));
  return u.v;
}

// async global->LDS, 16B per lane; LDS dest = wave-uniform base + lane*16
__device__ __forceinline__ void gload16(const void* g, void* l) {
  __builtin_amdgcn_global_load_lds(
      (__attribute__((address_space(1))) void*)g,
      (__attribute__((address_space(3))) void*)l, 16, 0, 0);
}

// non-temporal 8B store (outputs are never re-read in-kernel)
__device__ __forceinline__ void nt_store2(float* p, float x, float y) {
  f32x2 v; v[0] = x; v[1] = y;
  __builtin_nontemporal_store(v, (f32x2*)p);
}

// ---- prep: w (700x128 f32, k-major) -> w_t (128 x 704 bf16, zero-padded K) ----
__global__ void prep_wt(const float* __restrict__ w, ushort* __restrict__ w_t) {
  int idx = blockIdx.x * 256 + threadIdx.x;
  if (idx >= On * KP) return;
  int col = idx / KP, k = idx - col * KP;
  float v = (k < In) ? w[(size_t)k * On + col] : 0.0f;
  w_t[(size_t)col * KP + k] = (ushort)f2bf(v);
}

// ---- GEMM + fused per-segment local scan (phase A) ----
// 3-deep global_load_lds pipeline with counted vmcnt (loads stay in flight
// across raw s_barriers; never drain to 0 in the main loop).
union SMU {
  struct {
    uint32_t A[3][4096];   // 48 KB: fp32 tile 128 rows x 8 slots x 16B, src-swizzled
    uint32_t B[3][2048];   // 24 KB: bf16 tile 128 cols x 4 slots x 16B, src-swizzled
  } db;                    // 72 KB staging -> 2 blocks/CU
  float sc[128 * 132];     // 66 KB h/scan buffer (pad 132 vs 128)
};

__global__ __launch_bounds__(256, 2) void gemm_h(
    const float* __restrict__ A,    // 65536 x 700 f32
    const ushort* __restrict__ Wt,  // 128 x 704 bf16
    float* __restrict__ H,          // 65536 x 128 f32 (h -> later syn)
    float2* __restrict__ ep,        // [NSEG][BO] endpoints (may be null)
    const float* __restrict__ alpha, const float* __restrict__ beta)
{
  __shared__ __align__(16) SMU sm;

  const int tid  = threadIdx.x;
  const int bm   = blockIdx.x;        // 512 blocks: batch b = bm>>2, quarter = bm&3
  const int lane = tid & 63;
  const int wid  = tid >> 6;          // 4 waves, 2x2 wave grid (64x64 each)
  const int wm   = wid >> 1, wn = wid & 1;
  const int l16  = lane & 15, lkb = lane >> 4;

  // alpha/beta for phase A; drain so the counted vmcnt pipeline stays exact
  const int   o_ep = tid & 127;
  const float a_ep = alpha[o_ep];
  const float b_ep = beta[o_ep];
  WAITVM(0);
  __builtin_amdgcn_sched_barrier(0);

  f32x4 acc[4][4];
#pragma unroll
  for (int i = 0; i < 4; ++i)
#pragma unroll
    for (int n = 0; n < 4; ++n) acc[i][n] = (f32x4){0.f, 0.f, 0.f, 0.f};

  auto stage = [&](int bi, int kt) {   // 6 loads per wave
    const int k0 = kt * 32;
#pragma unroll
    for (int is = 0; is < 4; ++is) {
      const int q   = is * 256 + wid * 64 + lane;
      const int row = q >> 3, sl = q & 7;
      int gk = k0 + ((sl ^ (row & 7)) << 2);
      if (gk >= In) gk = k0;                        // clamp; Wt zero at k>=700
      gload16(A + (size_t)(bm * 128 + row) * In + gk,
              &sm.db.A[bi][is * 1024 + wid * 256]);
    }
#pragma unroll
    for (int is = 0; is < 2; ++is) {
      const int q   = is * 256 + wid * 64 + lane;
      const int col = q >> 2, sl = q & 3;
      const int ks  = sl ^ ((col >> 1) & 3);
      gload16(Wt + (size_t)col * KP + k0 + ks * 8,
              &sm.db.B[bi][is * 1024 + wid * 256]);
    }
  };

  auto tile = [&](int kt, int cur) {
    __builtin_amdgcn_s_barrier();
    const float4* Af = (const float4*)sm.db.A[cur];
    const bf16x8* Bf = (const bf16x8*)sm.db.B[cur];
    bf16x8 af[4], bfr[4];
#pragma unroll
    for (int i = 0; i < 4; ++i) {
      const int row = wm * 64 + i * 16 + l16;
      const int s0  = (lkb * 2) ^ (row & 7);
      const int s1  = (lkb * 2 + 1) ^ (row & 7);
      af[i] = cvt8(Af[row * 8 + s0], Af[row * 8 + s1]);
    }
#pragma unroll
    for (int n = 0; n < 4; ++n) {
      const int col = wn * 64 + n * 16 + l16;
      bfr[n] = Bf[col * 4 + (lkb ^ ((col >> 1) & 3))];
    }
    asm volatile("s_waitcnt lgkmcnt(0)" ::: "memory");
    __builtin_amdgcn_s_barrier();
    if (kt + 3 < NKT) stage(cur, kt + 3);   // overwrite just-consumed buffer
#pragma unroll
    for (int i = 0; i < 4; ++i)
#pragma unroll
      for (int n = 0; n < 4; ++n)
        acc[i][n] = __builtin_amdgcn_mfma_f32_16x16x32_bf16(af[i], bfr[n], acc[i][n], 0, 0, 0);
  };

  stage(0, 0); stage(1, 1); stage(2, 2);    // 18 loads/wave in flight
  {
    int cur = 0;
    for (int kt = 0; kt < NKT - 2; ++kt) {  // kt = 0..19: 3 tiles outstanding
      WAITVM(12);
      tile(kt, cur);
      cur = (cur == 2) ? 0 : cur + 1;
    }
    WAITVM(6);  tile(NKT - 2, (NKT - 2) % 3);
    WAITVM(0);  tile(NKT - 1, (NKT - 1) % 3);
  }

  // ---- epilogue: acc -> LDS (t-major, pad 132) ----
#pragma unroll
  for (int i = 0; i < 4; ++i)
#pragma unroll
    for (int n = 0; n < 4; ++n) {
      const int col = wn * 64 + n * 16 + l16;
#pragma unroll
      for (int r = 0; r < 4; ++r) {
        const int row = wm * 64 + i * 16 + lkb * 4 + r;
        sm.sc[row * 132 + col] = acc[i][n][r];
      }
    }
  __syncthreads();

  // coalesced float4 H write from LDS
  const size_t hbase = (size_t)bm * 128 * 128;
#pragma unroll
  for (int i2 = 0; i2 < 16; ++i2) {
    const int q = i2 * 256 + tid;
    const int row = q >> 5, v = q & 31;
    *(float4*)&H[hbase + row * 128 + v * 4] =
        *(const float4*)&sm.sc[row * 132 + v * 4];
  }

  // fused phase A: per-segment local scan from zero (4 segs x 128 cols)
  if (ep) {
    const float a = a_ep, bt = b_ep, omb = 1.0f - b_ep;
    const int b = bm >> 2, seg0 = (bm & 3) * 4;
#pragma unroll
    for (int cc = 0; cc < 2; ++cc) {
      const int sl = (tid >> 7) + cc * 2;
      float S = 0.f, M = 0.f;
      const float* base = &sm.sc[(sl * 32) * 132 + o_ep];
#pragma unroll
      for (int t = 0; t < 32; ++t) {
        const float x = base[t * 132];
        M = fmaf(bt, M, omb * S);   // uses OLD S
        S = fmaf(a, S, x);
      }
      ep[(size_t)(seg0 + sl) * BO + b * On + o_ep] = make_float2(S, M);
    }
  }
}

// ---- Phase B+C fused, float2-vectorized, NT output stores ----
__global__ __launch_bounds__(256) void scan_seg(
    float* __restrict__ syn, float* __restrict__ mem, const float2* __restrict__ ep,
    const float* __restrict__ alpha, const float* __restrict__ beta)
{
  const int cid = blockIdx.x * 256 + threadIdx.x;   // (b, seg, o2): 128*16*64
  const int o2  = cid & 63;                         // o-pair index (wave-uniform seg)
  const int seg = (cid >> 6) & (NSEG - 1);
  const int b   = cid >> 10;
  const int o   = 2 * o2;

  const float2 al2 = *(const float2*)&alpha[o];
  const float2 be2 = *(const float2*)&beta[o];
  const float a0 = al2.x, a1 = al2.y, b0 = be2.x, b1 = be2.y;
  const float ob0 = 1.f - b0, ob1 = 1.f - b1;

  // A^L coefficients (stable iteration)
  float aL0 = 1.f, bL0 = 1.f, cL0 = 0.f, aL1 = 1.f, bL1 = 1.f, cL1 = 0.f;
#pragma unroll
  for (int i = 0; i < LSEG; ++i) {
    cL0 = fmaf(b0, cL0, ob0 * aL0); aL0 *= a0; bL0 *= b0;
    cL1 = fmaf(b1, cL1, ob1 * aL1); aL1 *= a1; bL1 *= b1;
  }

  // prefix over preceding segment endpoints (wave-uniform trip count)
  float S0 = 0.f, M0 = 0.f, S1 = 0.f, M1 = 0.f;
  for (int j = 0; j < seg; ++j) {
    const float4 E = *(const float4*)&ep[(size_t)j * BO + b * On + o];
    const float nS0 = fmaf(aL0, S0, E.x);
    M0 = fmaf(bL0, M0, fmaf(cL0, S0, E.y));   // uses OLD S
    S0 = nS0;
    const float nS1 = fmaf(aL1, S1, E.z);
    M1 = fmaf(bL1, M1, fmaf(cL1, S1, E.w));
    S1 = nS1;
  }

  float* hp = syn + ((size_t)b * Tn + seg * LSEG) * On + o;  // holds h, becomes S
  float* mp = mem + ((size_t)b * Tn + seg * LSEG) * On + o;
  float2 buf[8];
#pragma unroll
  for (int d = 0; d < 8; ++d) buf[d] = *(const float2*)&hp[d * On];
  for (int tb = 0; tb < LSEG; tb += 8) {
#pragma unroll
    for (int d = 0; d < 8; ++d) {
      const int t = tb + d;
      const float2 x = buf[d];
      if (t + 8 < LSEG) buf[d] = *(const float2*)&hp[(t + 8) * On];
      nt_store2(&hp[(size_t)t * On], S0, S1);
      nt_store2(&mp[(size_t)t * On], M0, M1);
      M0 = fmaf(b0, M0, ob0 * S0); S0 = fmaf(a0, S0, x.x);   // M uses OLD S
      M1 = fmaf(b1, M1, ob1 * S1); S1 = fmaf(a1, S1, x.y);
    }
  }
}

// ---- fallback single-pass scan (used only if ws_size is too small) ----
__global__ __launch_bounds__(64) void scan_k(
    float* __restrict__ syn, float* __restrict__ mem,
    const float* __restrict__ alpha, const float* __restrict__ beta)
{
  const int b = blockIdx.x >> 1;
  const int o = ((blockIdx.x & 1) << 6) + threadIdx.x;
  const float a = alpha[o], bt = beta[o], omb = 1.0f - bt;
  float* hp = syn + (size_t)b * Tn * On + o;
  float* mp = mem + (size_t)b * Tn * On + o;
  float S = 0.f, M = 0.f;
  float buf[8];
#pragma unroll
  for (int d = 0; d < 8; ++d) buf[d] = hp[d * On];
  for (int tb = 0; tb < Tn; tb += 8) {
#pragma unroll
    for (int d = 0; d < 8; ++d) {
      const int t = tb + d;
      const float h_t = buf[d];
      if (t + 8 < Tn) buf[d] = hp[(t + 8) * On];
      hp[t * On] = S;
      mp[t * On] = M;
      const float nS = fmaf(a, S, h_t);
      M = fmaf(bt, M, omb * S);
      S = nS;
    }
  }
}

extern "C" void kernel_launch(void* const* d_in, const int* in_sizes, int n_in,
                              void* d_out, int out_size, void* d_ws, size_t ws_size,
                              hipStream_t stream) {
  const float* inputs = (const float*)d_in[0];   // (128,512,700)
  const float* w      = (const float*)d_in[1];   // (700,128)
  const float* alpha  = (const float*)d_in[2];   // (1,128)
  const float* beta   = (const float*)d_in[3];   // (1,128)

  float* syn = (float*)d_out;                    // first 8M floats
  float* mem = syn + (size_t)Bsz * Tn * On;      // next 8M floats
  ushort* w_t = (ushort*)mem;                    // 180 KB temp in mem region,
                                                 // consumed by gemm before scan writes

  const size_t ep_bytes = (size_t)NSEG * BO * sizeof(float2);  // 2 MB
  float2* ep = (ws_size >= ep_bytes) ? (float2*)d_ws : nullptr;

  prep_wt<<<(On * KP + 255) / 256, 256, 0, stream>>>(w, w_t);
  gemm_h<<<Mn / 128, 256, 0, stream>>>(inputs, w_t, syn, ep, alpha, beta);

  if (ep) {
    scan_seg<<<(Bsz * NSEG * On / 2) / 256, 256, 0, stream>>>(syn, mem, ep, alpha, beta);
  } else {
    scan_k<<<Bsz * 2, 64, 0, stream>>>(syn, mem, alpha, beta);
  }
}